// Round 4
// baseline (399.854 us; speedup 1.0000x reference)
//
#include <hip/hip_runtime.h>

// RotaryPositionEncoding3D: out[b,n,f,c] with f = bin*6 + axis*2 + dup,
// c = 0 (cos) / 1 (sin). One output float4 (point, bin, axis) = (cos,sin,cos,sin).
//
// Round-7 = round-6 resubmitted (container infra failure, kernel never ran).
// Persistent-wave shape: round-5 showed the kernel pinned at ~2.8 TB/s
// regardless of inner-loop instruction count. The co-resident fill kernel
// hits 6.2 TB/s at ~3 waves/CU with long-lived waves; we were launching 49k
// short-lived waves (8 stores each, prologue per block).
// Now: grid = 768 blocks (3/CU), each thread does 128 grid-stride iterations.
// stride = 768*256 = 196608 ≡ 0 (mod 96) so (bin, axis, d) stay loop-invariant.
// 25165824 / 196608 = 128 exactly -> no tail for the bench shape.

typedef float vfloat4 __attribute__((ext_vector_type(4)));

#define CHUNK 8

__global__ __launch_bounds__(256) void rope3d_kernel(
    const float* __restrict__ xyz,       // [P, 3]
    const float* __restrict__ div_term,  // [32]
    vfloat4* __restrict__ out,           // [P * 96] float4s
    int total_f4)
{
    __shared__ float s_div[32];
    if (threadIdx.x < 32) s_div[threadIdx.x] = div_term[threadIdx.x];
    __syncthreads();

    const int stride = blockDim.x * gridDim.x;   // ≡ 0 (mod 96)
    int g = blockIdx.x * blockDim.x + threadIdx.x;

    // One-time decomposition; (bin, axis) invariant because stride % 96 == 0.
    unsigned int ug   = (unsigned int)g;
    unsigned int p    = ug / 96u;          // point index (magic mul, once)
    unsigned int q    = ug - p * 96u;      // [0,96)
    unsigned int bin  = q / 3u;            // frequency bin [0,32)
    unsigned int axis = q - bin * 3u;      // 0=x 1=y 2=z

    const float d       = s_div[bin];
    const int   cstride = stride >> 5;     // (stride/96)*3 == stride/32
    int         cidx    = (int)(p * 3u + axis);

    // Main loop: chunks of 8 iterations, loads batched ahead of sincos+store.
    while (g + (CHUNK - 1) * stride < total_f4) {
        float coord[CHUNK];
#pragma unroll
        for (int k = 0; k < CHUNK; ++k) {
            coord[k] = xyz[cidx];
            cidx += cstride;
        }
#pragma unroll
        for (int k = 0; k < CHUNK; ++k) {
            float ang = coord[k] * d;      // |ang| <= 1
            float s = __sinf(ang);
            float c = __cosf(ang);
            vfloat4 v = {c, s, c, s};
            __builtin_nontemporal_store(v, &out[g]);
            g += stride;
        }
    }
    // Tail (not taken for the bench shape; kept for generality).
    while (g < total_f4) {
        float ang = xyz[cidx] * d;
        float s = __sinf(ang);
        float c = __cosf(ang);
        vfloat4 v = {c, s, c, s};
        __builtin_nontemporal_store(v, &out[g]);
        cidx += cstride;
        g += stride;
    }
}

extern "C" void kernel_launch(void* const* d_in, const int* in_sizes, int n_in,
                              void* d_out, int out_size, void* d_ws, size_t ws_size,
                              hipStream_t stream) {
    const float* xyz      = (const float*)d_in[0];  // [B*N*3]
    const float* div_term = (const float*)d_in[1];  // [32]
    float*       out      = (float*)d_out;          // [B*N*192*2]

    int points   = in_sizes[0] / 3;       // B*N
    int total_f4 = points * 96;           // out_size / 4

    const int block = 256;
    // Persistent shape: ~3 blocks/CU. Multiple of 3 -> stride % 96 == 0.
    int grid = 768;
    int max_grid = (total_f4 + block - 1) / block;
    if (grid > max_grid) grid = ((max_grid + 2) / 3) * 3;  // small-input safety
    rope3d_kernel<<<grid, block, 0, stream>>>(xyz, div_term, (vfloat4*)out, total_f4);
}

// Round 5
// 396.819 us; speedup vs baseline: 1.0076x; 1.0076x over previous
//
#include <hip/hip_runtime.h>

// RotaryPositionEncoding3D: out[b,n,f,c] with f = bin*6 + axis*2 + dup,
// c = 0 (cos) / 1 (sin). One output float4 (point, bin, axis) = (cos,sin,cos,sin).
//
// Round-8 change: isolate the store path. Round-5 changed thinning AND
// nontemporal stores together; rounds 6/7 kept nt and were null. This round
// uses REGULAR write-back stores (like the 6.2 TB/s fill kernel) to test
// whether nt was de-rating the store stream. Also: s_div holds
// div_term * 1/(2*pi) and we call raw v_sin/v_cos (revolution input) via
// __builtin_amdgcn_sinf/cosf, shaving the 2 range-conversion muls.

typedef float vfloat4 __attribute__((ext_vector_type(4)));

#define CHUNK 8

__global__ __launch_bounds__(256) void rope3d_kernel(
    const float* __restrict__ xyz,       // [P, 3]
    const float* __restrict__ div_term,  // [32]
    vfloat4* __restrict__ out,           // [P * 96] float4s
    int total_f4)
{
    __shared__ float s_div[32];
    if (threadIdx.x < 32)
        s_div[threadIdx.x] = div_term[threadIdx.x] * 0.15915494309189535f; // 1/(2*pi)
    __syncthreads();

    const int stride = blockDim.x * gridDim.x;   // ≡ 0 (mod 96)
    int g = blockIdx.x * blockDim.x + threadIdx.x;

    // One-time decomposition; (bin, axis) invariant because stride % 96 == 0.
    unsigned int ug   = (unsigned int)g;
    unsigned int p    = ug / 96u;          // point index (magic mul, once)
    unsigned int q    = ug - p * 96u;      // [0,96)
    unsigned int bin  = q / 3u;            // frequency bin [0,32)
    unsigned int axis = q - bin * 3u;      // 0=x 1=y 2=z

    const float d       = s_div[bin];      // pre-scaled: ang in revolutions
    const int   cstride = stride >> 5;     // (stride/96)*3 == stride/32
    int         cidx    = (int)(p * 3u + axis);

    // Main loop: chunks of 8 iterations, loads batched ahead of sincos+store.
    while (g + (CHUNK - 1) * stride < total_f4) {
        float coord[CHUNK];
#pragma unroll
        for (int k = 0; k < CHUNK; ++k) {
            coord[k] = xyz[cidx];
            cidx += cstride;
        }
#pragma unroll
        for (int k = 0; k < CHUNK; ++k) {
            float ang = coord[k] * d;      // revolutions, |ang| <= 0.16
            float s = __builtin_amdgcn_sinf(ang);
            float c = __builtin_amdgcn_cosf(ang);
            vfloat4 v = {c, s, c, s};
            out[g] = v;                    // regular write-back store
            g += stride;
        }
    }
    // Tail (not taken for the bench shape; kept for generality).
    while (g < total_f4) {
        float ang = xyz[cidx] * d;
        float s = __builtin_amdgcn_sinf(ang);
        float c = __builtin_amdgcn_cosf(ang);
        vfloat4 v = {c, s, c, s};
        out[g] = v;
        cidx += cstride;
        g += stride;
    }
}

extern "C" void kernel_launch(void* const* d_in, const int* in_sizes, int n_in,
                              void* d_out, int out_size, void* d_ws, size_t ws_size,
                              hipStream_t stream) {
    const float* xyz      = (const float*)d_in[0];  // [B*N*3]
    const float* div_term = (const float*)d_in[1];  // [32]
    float*       out      = (float*)d_out;          // [B*N*192*2]

    int points   = in_sizes[0] / 3;       // B*N
    int total_f4 = points * 96;           // out_size / 4

    const int block = 256;
    // Persistent shape: ~3 blocks/CU. Multiple of 3 -> stride % 96 == 0.
    int grid = 768;
    int max_grid = (total_f4 + block - 1) / block;
    if (grid > max_grid) grid = ((max_grid + 2) / 3) * 3;  // small-input safety
    rope3d_kernel<<<grid, block, 0, stream>>>(xyz, div_term, (vfloat4*)out, total_f4);
}